// Round 6
// baseline (228.115 us; speedup 1.0000x reference)
//
#include <hip/hip_runtime.h>
#include <hip/hip_bf16.h>

namespace {

constexpr int kB = 512, kT = 512, kN = 128, kM = 64, kU = 64;
constexpr int TT = 64;          // t-tile per staging round
constexpr int SX = 68;          // row stride (u32): 68 mod 32 = 4 -> bank-spread, 16B-aligned

typedef __attribute__((ext_vector_type(8))) short short8;    // bf16x8 MFMA frag (4 VGPR)
typedef __attribute__((ext_vector_type(16))) float f32x16;   // 32x32 MFMA acc

// f32 -> (bf16 hi | bf16 lo) packed in one u32. hi = rne(v); lo = rne(v - hi).
__device__ __forceinline__ unsigned pack_hl(float v) {
  unsigned u = __float_as_uint(v);
  unsigned hs = (u + 0x7fffu + ((u >> 16) & 1u)) >> 16;
  float lo = v - __uint_as_float(hs << 16);
  unsigned ul = __float_as_uint(lo);
  unsigned ls = (ul + 0x7fffu + ((ul >> 16) & 1u)) >> 16;
  return (hs << 16) | (ls & 0xffffu);
}

__device__ __forceinline__ float fast_tanh(float x) {
  return 1.0f - 2.0f / (__expf(2.0f * x) + 1.0f);
}

union FragU { unsigned u[4]; short8 s; };

// 8 packed u32 (k-consecutive) -> hi frag + lo frag, element order preserved.
__device__ __forceinline__ void unpack_hl(const unsigned* p, short8& hi, short8& lo) {
  FragU H, L;
#pragma unroll
  for (int j = 0; j < 4; ++j) {
    unsigned a = p[2 * j], b = p[2 * j + 1];
    H.u[j] = (a >> 16) | (b & 0xffff0000u);
    L.u[j] = (a & 0xffffu) | (b << 16);
  }
  hi = H.s; lo = L.s;
}

struct __align__(16) SmemS {
  unsigned xsT[kN * SX];   // x-tile transposed [n][t], packed hi|lo  (34816 B)
  unsigned w1T[kU * SX];   // w1-tile transposed [u][t], packed hi|lo (17408 B)
  float qpart[8][kU];      // q_proj partials (2 KB)
  float sred[2][kN];       // per-u-tile score partials
  float sn[kN];
};

// One block per batch. 512 threads = 8 waves.
// Wave w owns output tile: n in [32*(w&3), +32), u in [32*(w>>2), +32).
// Staging: b32 global loads, one LDS row per lane -> conflict-free transpose.
__global__ __launch_bounds__(512, 4) void score_kernel(
    const float* __restrict__ x,    // (B,T,N)
    const float* __restrict__ hs,   // (B,M)
    const float* __restrict__ cs,   // (B,M)
    const float* __restrict__ w1,   // (T,U)
    const float* __restrict__ w1b,  // (U)
    const float* __restrict__ w2,   // (2M,U)
    const float* __restrict__ w2b,  // (U)
    const float* __restrict__ vk,   // (U,1)
    float* __restrict__ aw_out)     // (B,1,N) f32 — also consumed by kernel 2
{
  __shared__ SmemS s;
  const int b = blockIdx.x;
  const int tid = threadIdx.x;
  const int l = tid & 63;
  const int w = tid >> 6;

  // ---- Phase 0: q_proj partials, all 512 threads (16 k-terms each) ----
  {
    const int u = tid & 63, kg = tid >> 6;   // k range kg*16..+15
    float a0 = 0.f;
#pragma unroll
    for (int j = 0; j < 16; ++j) {
      int k = kg * 16 + j;
      float qv = (k < kM) ? hs[(size_t)b * kM + k] : cs[(size_t)b * kM + (k - kM)];
      a0 = fmaf(qv, w2[k * kU + u], a0);
    }
    s.qpart[kg][u] = a0;
  }

  // staging identities: x col xn (one LDS row per thread), t-rows xts..xts+15
  const int xn = l + 64 * (w & 1);
  const int xts = (w >> 1) * 16;
  // w1: col wu, t-rows wts..wts+7
  const int wu = l;
  const int wts = w * 8;

  // MFMA identities
  const int kh = l >> 5;                    // k-half selector
  const int mrow = (w & 3) * 32 + (l & 31); // A row (n)
  const int urow = (w >> 2) * 32 + (l & 31);// B col (u)

  f32x16 acc;
#pragma unroll
  for (int i = 0; i < 16; ++i) acc[i] = 0.f;

  float rx[16], rw[8];
  // preload tile 0
#pragma unroll
  for (int j = 0; j < 16; ++j)
    rx[j] = x[((size_t)b * kT + xts + j) * kN + xn];
#pragma unroll
  for (int j = 0; j < 8; ++j)
    rw[j] = w1[(size_t)(wts + j) * kU + wu];

  for (int t0 = 0; t0 < kT; t0 += TT) {
    __syncthreads();   // prev K-loop reads done
    // pack + transposed store: one b128 row-segment per write, banks spread by row
    {
      unsigned px[16];
#pragma unroll
      for (int j = 0; j < 16; ++j) px[j] = pack_hl(rx[j]);
#pragma unroll
      for (int jj = 0; jj < 4; ++jj)
        *(uint4*)&s.xsT[xn * SX + xts + 4 * jj] =
            make_uint4(px[4 * jj], px[4 * jj + 1], px[4 * jj + 2], px[4 * jj + 3]);
      unsigned pw[8];
#pragma unroll
      for (int j = 0; j < 8; ++j) pw[j] = pack_hl(rw[j]);
#pragma unroll
      for (int jj = 0; jj < 2; ++jj)
        *(uint4*)&s.w1T[wu * SX + wts + 4 * jj] =
            make_uint4(pw[4 * jj], pw[4 * jj + 1], pw[4 * jj + 2], pw[4 * jj + 3]);
    }
    __syncthreads();
    // prefetch next tile: loads in flight under the K-loop
    if (t0 + TT < kT) {
#pragma unroll
      for (int j = 0; j < 16; ++j)
        rx[j] = x[((size_t)b * kT + t0 + TT + xts + j) * kN + xn];
#pragma unroll
      for (int j = 0; j < 8; ++j)
        rw[j] = w1[(size_t)(t0 + TT + wts + j) * kU + wu];
    }

    // K-loop: 4 steps of k=16; split-bf16 3-term MFMA 32x32x16
#pragma unroll
    for (int ss = 0; ss < 4; ++ss) {
      unsigned ra[8];
      const unsigned* pa = &s.xsT[mrow * SX + 16 * ss + 8 * kh];
      *(uint4*)&ra[0] = *(const uint4*)pa;
      *(uint4*)&ra[4] = *(const uint4*)(pa + 4);
      short8 ah, al;
      unpack_hl(ra, ah, al);

      unsigned rb[8];
      const unsigned* pb = &s.w1T[urow * SX + 16 * ss + 8 * kh];
      *(uint4*)&rb[0] = *(const uint4*)pb;
      *(uint4*)&rb[4] = *(const uint4*)(pb + 4);
      short8 bh, bl;
      unpack_hl(rb, bh, bl);

      acc = __builtin_amdgcn_mfma_f32_32x32x16_bf16(ah, bh, acc, 0, 0, 0);
      acc = __builtin_amdgcn_mfma_f32_32x32x16_bf16(ah, bl, acc, 0, 0, 0);
      acc = __builtin_amdgcn_mfma_f32_32x32x16_bf16(al, bh, acc, 0, 0, 0);
    }
  }

  // ---- Phase 2: tanh, *v, reduce over u; softmax ----
  // Lane: u = urow (fixed), n rows = (w&3)*32 + (r&3) + 8*(r>>2) + 4*kh.
  float qpu = w2b[urow] + w1b[urow];
#pragma unroll
  for (int g = 0; g < 8; ++g) qpu += s.qpart[g][urow];
  const float vu = vk[urow];

  float pr[16];
#pragma unroll
  for (int r = 0; r < 16; ++r)
    pr[r] = fast_tanh(acc[r] + qpu) * vu;
  // sum over the 32 u-lanes (bits 0..4 of lane id)
#pragma unroll
  for (int off = 1; off < 32; off <<= 1)
#pragma unroll
    for (int r = 0; r < 16; ++r)
      pr[r] += __shfl_xor(pr[r], off);

  if ((l & 31) == 0) {
#pragma unroll
    for (int r = 0; r < 16; ++r)
      s.sred[w >> 2][(w & 3) * 32 + (r & 3) + 8 * (r >> 2) + 4 * kh] = pr[r];
  }
  __syncthreads();
  if (tid < kN) s.sn[tid] = s.sred[0][tid] + s.sred[1][tid];
  __syncthreads();

  if (tid < 64) {   // wave 0: softmax over 128 (v_bias shift cancels)
    float s0 = s.sn[tid], s1 = s.sn[tid + 64];
    float m = fmaxf(s0, s1);
#pragma unroll
    for (int off = 32; off > 0; off >>= 1) m = fmaxf(m, __shfl_xor(m, off));
    float e0 = __expf(s0 - m), e1 = __expf(s1 - m);
    float se = e0 + e1;
#pragma unroll
    for (int off = 32; off > 0; off >>= 1) se += __shfl_xor(se, off);
    float inv = 1.0f / se;
    aw_out[(size_t)b * kN + tid] = e0 * inv;
    aw_out[(size_t)b * kN + tid + 64] = e1 * inv;
  }
}

// ctx[b,t] = sum_n aw[n] * x[b,t,n]. 4 blocks per batch (128 rows each),
// 256 threads, quad-per-row. aw read from the f32 aw_out region of d_out.
__global__ __launch_bounds__(256) void context_kernel(
    const float* __restrict__ x,
    const float* __restrict__ aw_in,   // (B,N) f32
    float* __restrict__ ctx)           // (B,T) f32
{
  __shared__ float aw[kN];
  const int b = blockIdx.x >> 2;
  const int seg = blockIdx.x & 3;
  if (threadIdx.x < kN) aw[threadIdx.x] = aw_in[(size_t)b * kN + threadIdx.x];
  __syncthreads();

  const int lr = threadIdx.x & 3;
  const int row = threadIdx.x >> 2;   // 0..63
#pragma unroll
  for (int rg = 0; rg < 2; ++rg) {
    const int r = seg * 128 + rg * 64 + row;
    const float4* xp = (const float4*)(x + ((size_t)b * kT + r) * kN);
    float a = 0.f;
#pragma unroll
    for (int k = 0; k < 8; ++k) {
      int i = lr + k * 4;              // 32 float4 per row, quad-covered
      float4 v = xp[i];
      const float* wa = &aw[i * 4];
      a = fmaf(v.x, wa[0], a);
      a = fmaf(v.y, wa[1], a);
      a = fmaf(v.z, wa[2], a);
      a = fmaf(v.w, wa[3], a);
    }
    a += __shfl_xor(a, 1);
    a += __shfl_xor(a, 2);
    if (lr == 0) ctx[(size_t)b * kT + r] = a;
  }
}

}  // namespace

extern "C" void kernel_launch(void* const* d_in, const int* in_sizes, int n_in,
                              void* d_out, int out_size, void* d_ws, size_t ws_size,
                              hipStream_t stream) {
  const float* x   = (const float*)d_in[0];
  const float* hs  = (const float*)d_in[1];
  const float* cs  = (const float*)d_in[2];
  const float* w1  = (const float*)d_in[3];
  const float* w1b = (const float*)d_in[4];
  const float* w2  = (const float*)d_in[5];
  const float* w2b = (const float*)d_in[6];
  const float* vk  = (const float*)d_in[7];

  float* out = (float*)d_out;
  float* ctx = out;                      // context_vector (B,T)
  float* awo = out + (size_t)kB * kT;    // attention_weights (B,1,N)

  hipLaunchKernelGGL(score_kernel, dim3(kB), dim3(512), 0, stream,
                     x, hs, cs, w1, w1b, w2, w2b, vk, awo);
  hipLaunchKernelGGL(context_kernel, dim3(kB * 4), dim3(256), 0, stream,
                     x, awo, ctx);
}

// Round 7
// 222.010 us; speedup vs baseline: 1.0275x; 1.0275x over previous
//
#include <hip/hip_runtime.h>
#include <hip/hip_bf16.h>

namespace {

constexpr int kB = 512, kT = 512, kN = 128, kM = 64, kU = 64;
constexpr int WST = 72;    // w1 stage row stride (u32): 2 groups x 32 + pad, 16B-aligned
constexpr int XST = 520;   // persisted-x row stride (u16): 512 + 8 pad
constexpr int RST = 12;    // acc-reduction row stride (f32)
constexpr int CST = 528;   // ctx-reduction row stride (f32)

typedef __attribute__((ext_vector_type(8))) short short8;    // bf16x8 MFMA frag
typedef __attribute__((ext_vector_type(16))) float f32x16;   // 32x32 MFMA acc

__device__ __forceinline__ unsigned rne16(float v) {
  unsigned u = __float_as_uint(v);
  return (u + 0x7fffu + ((u >> 16) & 1u)) >> 16;
}
__device__ __forceinline__ float fb16(unsigned h) { return __uint_as_float(h << 16); }

// w1 LDS element format: hi bf16 in top 16, lo bf16 in bottom 16 (round-6 format).
__device__ __forceinline__ unsigned pack_hl(float v) {
  unsigned h = rne16(v);
  unsigned l = rne16(v - fb16(h));
  return (h << 16) | (l & 0xffffu);
}

__device__ __forceinline__ float fast_tanh(float x) {
  return 1.0f - 2.0f / (__expf(2.0f * x) + 1.0f);
}

union FragU { unsigned u[4]; short8 s; };

// 8 packed u32 (k-order) -> hi/lo frags; element 2j low-half, 2j+1 high (round-6 verified).
__device__ __forceinline__ void unpack_hl(const unsigned* p, short8& hi, short8& lo) {
  FragU H, L;
#pragma unroll
  for (int j = 0; j < 4; ++j) {
    unsigned a = p[2 * j], b = p[2 * j + 1];
    H.u[j] = (a >> 16) | (b & 0xffff0000u);
    L.u[j] = (a & 0xffffu) | (b << 16);
  }
  hi = H.s; lo = L.s;
}

// 8 f32 -> hi/lo frags directly (same element order as unpack_hl's output).
__device__ __forceinline__ void pack8(const float* v, short8& hi, short8& lo) {
  FragU H, L;
#pragma unroll
  for (int jj = 0; jj < 4; ++jj) {
    float v0 = v[2 * jj], v1 = v[2 * jj + 1];
    unsigned h0 = rne16(v0), h1 = rne16(v1);
    unsigned l0 = rne16(v0 - fb16(h0)), l1 = rne16(v1 - fb16(h1));
    H.u[jj] = h0 | (h1 << 16);
    L.u[jj] = l0 | (l1 << 16);
  }
  hi = H.s; lo = L.s;
}

struct Smem {
  union {
    unsigned wstage[kU * WST];        // 18432 B: w1 sub-tile, packed+swizzled
    float red[256 * RST];             // 12288 B: cross-kgroup acc reduction
    float red2[8 * CST];              // 16896 B: ctx cross-wave reduction
  } u;
  unsigned short xbf[kN * XST];       // 133120 B: x persisted as bf16 [n][t]
  float qpart[8][kU];
  float qpfull[kU];
  float sn[kN];
  float aw[kN];
};                                    // total 154,880 B (dynamic LDS)

// One block per batch. 512 threads = 8 waves.
// Wave w: kgroup g=w>>2 (t half), m-tile m=w&3 (n in [32m,32m+32)), both u-tiles.
__global__ __launch_bounds__(512, 2) void fused_kernel(
    const float* __restrict__ x,    // (B,T,N)
    const float* __restrict__ hs,   // (B,M)
    const float* __restrict__ cs,   // (B,M)
    const float* __restrict__ w1,   // (T,U)
    const float* __restrict__ w1b,  // (U)
    const float* __restrict__ w2,   // (2M,U)
    const float* __restrict__ w2b,  // (U)
    const float* __restrict__ vk,   // (U,1)
    float* __restrict__ ctx_out,    // (B,T)
    float* __restrict__ aw_out)     // (B,1,N)
{
  extern __shared__ char smem_raw[];
  Smem& s = *reinterpret_cast<Smem*>(smem_raw);

  const int b = blockIdx.x;
  const int tid = threadIdx.x;
  const int l = tid & 63;
  const int w = tid >> 6;
  const int g = w >> 2;
  const int m = w & 3;
  const int ln = l & 31;
  const int kh = l >> 5;
  const int nA = 32 * m + ln;     // this lane's A row (n)

  // ---- Phase 0: q_proj partials (round-6 verified) ----
  {
    const int u = tid & 63, kg = tid >> 6;
    float a0 = 0.f;
#pragma unroll
    for (int j = 0; j < 16; ++j) {
      int k = kg * 16 + j;
      float qv = (k < kM) ? hs[(size_t)b * kM + k] : cs[(size_t)b * kM + (k - kM)];
      a0 = fmaf(qv, w2[k * kU + u], a0);
    }
    s.qpart[kg][u] = a0;
  }

  f32x16 acc0, acc1;
#pragma unroll
  for (int i = 0; i < 16; ++i) { acc0[i] = 0.f; acc1[i] = 0.f; }

  // ---- Phase 1: 8 sub-tiles of 32 t per kgroup ----
  for (int sub = 0; sub < 8; ++sub) {
    const int tb = g * 256 + sub * 32;
    __syncthreads();   // prev sub's wstage reads done (also covers qpart, 1st iter)

    // A: direct global loads, 2 k-steps x 8 (coalesced 128B per 32 lanes)
    float rA[2][8];
#pragma unroll
    for (int ks = 0; ks < 2; ++ks)
#pragma unroll
      for (int j = 0; j < 8; ++j)
        rA[ks][j] = x[((size_t)b * kT + tb + ks * 16 + 8 * kh + j) * kN + nA];

    // w1 stage: both kgroups' 32-t slices, packed + XOR-swizzled
#pragma unroll
    for (int i = 0; i < 8; ++i) {
      int idx = tid + i * 512;                 // 4096 = 64 trows x 64 u
      int u = idx & 63, tr = idx >> 6;
      int gg = tr >> 5, lt = tr & 31;
      float v = w1[(size_t)(gg * 256 + sub * 32 + lt) * kU + u];
      s.u.wstage[u * WST + 36 * gg + (lt ^ ((u & 7) << 2))] = pack_hl(v);
    }
    __syncthreads();

#pragma unroll
    for (int ks = 0; ks < 2; ++ks) {
      short8 ah, al;
      pack8(rA[ks], ah, al);
      const int tcur = tb + ks * 16 + 8 * kh;
      *(short8*)&s.xbf[nA * XST + tcur] = ah;   // persist bf16 x for context
      const int ltk = ks * 16 + 8 * kh;         // col within this group's 32
#pragma unroll
      for (int ut = 0; ut < 2; ++ut) {
        const int u = 32 * ut + ln;
        const int sw = (u & 7) << 2;
        const unsigned* base = &s.u.wstage[u * WST + 36 * g];
        unsigned rb[8];
        *(uint4*)&rb[0] = *(const uint4*)&base[ltk ^ sw];
        *(uint4*)&rb[4] = *(const uint4*)&base[(ltk + 4) ^ sw];
        short8 bh, bl;
        unpack_hl(rb, bh, bl);
        f32x16& a = ut ? acc1 : acc0;
        a = __builtin_amdgcn_mfma_f32_32x32x16_bf16(ah, bh, a, 0, 0, 0);
        a = __builtin_amdgcn_mfma_f32_32x32x16_bf16(ah, bl, a, 0, 0, 0);
        a = __builtin_amdgcn_mfma_f32_32x32x16_bf16(al, bh, a, 0, 0, 0);
      }
    }
  }
  __syncthreads();   // K done; wstage region free

  // ---- Cross-kgroup partial-pre reduction (4 rounds of 8 f32) ----
  const int rrow = ((w & 3) * 64 + l) * RST;
#pragma unroll
  for (int rnd = 0; rnd < 4; ++rnd) {
    f32x16& a = (rnd < 2) ? acc0 : acc1;
    const int off = (rnd & 1) * 8;
    if (g == 1) {
#pragma unroll
      for (int j = 0; j < 8; ++j) s.u.red[rrow + j] = a[off + j];
    }
    __syncthreads();
    if (g == 0) {
#pragma unroll
      for (int j = 0; j < 8; ++j) a[off + j] += s.u.red[rrow + j];
    }
    __syncthreads();
  }

  // ---- qpfull ----
  if (tid < kU) {
    float v = w2b[tid] + w1b[tid];
#pragma unroll
    for (int gg = 0; gg < 8; ++gg) v += s.qpart[gg][tid];
    s.qpfull[tid] = v;
  }
  __syncthreads();

  // ---- Phase 2: tanh + *v, reduce over u; g0 waves only ----
  if (g == 0) {
    const float qp0 = s.qpfull[ln], qp1 = s.qpfull[32 + ln];
    const float v0 = vk[ln], v1 = vk[32 + ln];
    float pr[16];
#pragma unroll
    for (int r = 0; r < 16; ++r)
      pr[r] = fmaf(fast_tanh(acc0[r] + qp0), v0, fast_tanh(acc1[r] + qp1) * v1);
#pragma unroll
    for (int off = 1; off < 32; off <<= 1)
#pragma unroll
      for (int r = 0; r < 16; ++r)
        pr[r] += __shfl_xor(pr[r], off);
    if (ln == 0) {
#pragma unroll
      for (int r = 0; r < 16; ++r)
        s.sn[32 * m + (r & 3) + 8 * (r >> 2) + 4 * kh] = pr[r];
    }
  }
  __syncthreads();

  // ---- Softmax over n=128 (wave 0); v_bias shift cancels ----
  if (tid < 64) {
    float s0 = s.sn[tid], s1 = s.sn[tid + 64];
    float mx = fmaxf(s0, s1);
#pragma unroll
    for (int off = 32; off > 0; off >>= 1) mx = fmaxf(mx, __shfl_xor(mx, off));
    float e0 = __expf(s0 - mx), e1 = __expf(s1 - mx);
    float se = e0 + e1;
#pragma unroll
    for (int off = 32; off > 0; off >>= 1) se += __shfl_xor(se, off);
    float inv = 1.0f / se;
    float a0 = e0 * inv, a1 = e1 * inv;
    s.aw[tid] = a0;
    s.aw[tid + 64] = a1;
    aw_out[(size_t)b * kN + tid] = a0;
    aw_out[(size_t)b * kN + tid + 64] = a1;
  }
  __syncthreads();

  // ---- Phase 3: ctx from persisted bf16 x (LDS only) ----
  {
    // wave w: n in [16w,16w+16); lane l: t in [8l, 8l+8)
    float cp[8];
#pragma unroll
    for (int j = 0; j < 8; ++j) cp[j] = 0.f;
    const int nb = 16 * w;
#pragma unroll
    for (int nn = 0; nn < 16; ++nn) {
      const int n = nb + nn;
      const float a = s.aw[n];
      short8 xv = *(const short8*)&s.xbf[n * XST + 8 * l];
#pragma unroll
      for (int j = 0; j < 8; ++j)
        cp[j] = fmaf(fb16((unsigned)(unsigned short)xv[j]), a, cp[j]);
    }
    float4 c0 = {cp[0], cp[1], cp[2], cp[3]};
    float4 c1 = {cp[4], cp[5], cp[6], cp[7]};
    *(float4*)&s.u.red2[w * CST + 8 * l] = c0;
    *(float4*)&s.u.red2[w * CST + 8 * l + 4] = c1;
  }
  __syncthreads();
  {
    float c = 0.f;
#pragma unroll
    for (int ww = 0; ww < 8; ++ww) c += s.u.red2[ww * CST + tid];
    ctx_out[(size_t)b * kT + tid] = c;
  }
}

}  // namespace

extern "C" void kernel_launch(void* const* d_in, const int* in_sizes, int n_in,
                              void* d_out, int out_size, void* d_ws, size_t ws_size,
                              hipStream_t stream) {
  const float* x   = (const float*)d_in[0];
  const float* hs  = (const float*)d_in[1];
  const float* cs  = (const float*)d_in[2];
  const float* w1  = (const float*)d_in[3];
  const float* w1b = (const float*)d_in[4];
  const float* w2  = (const float*)d_in[5];
  const float* w2b = (const float*)d_in[6];
  const float* vk  = (const float*)d_in[7];

  float* out = (float*)d_out;
  float* ctx = out;                      // context_vector (B,T)
  float* awo = out + (size_t)kB * kT;    // attention_weights (B,1,N)

  static_assert(sizeof(Smem) <= 160 * 1024, "LDS overflow");
  (void)hipFuncSetAttribute(reinterpret_cast<const void*>(fused_kernel),
                            hipFuncAttributeMaxDynamicSharedMemorySize,
                            (int)sizeof(Smem));
  hipLaunchKernelGGL(fused_kernel, dim3(kB), dim3(512), sizeof(Smem), stream,
                     x, hs, cs, w1, w1b, w2, w2b, vk, ctx, awo);
}